// Round 1
// baseline (2637.847 us; speedup 1.0000x reference)
//
#include <hip/hip_runtime.h>
#include <hip/hip_bf16.h>
#include <math.h>

#define C 128
#define K 16
#define TM 32

// ---------------------------------------------------------------------------
// Kernel 1: h = x@W_top + b_top; phi/psi/alpha = h@W_* + b_*   (N x C each)
// One 128-thread block handles TM=32 rows. Thread c owns output column c.
// LDS broadcast reads (all lanes same addr) for the activation tile.
// ---------------------------------------------------------------------------
__global__ __launch_bounds__(128) void k_qkv(
    const float* __restrict__ x,
    const float* __restrict__ Wt, const float* __restrict__ bt,
    const float* __restrict__ Wp, const float* __restrict__ bp,
    const float* __restrict__ Ws, const float* __restrict__ bs,
    const float* __restrict__ Wa, const float* __restrict__ ba,
    float* __restrict__ phi, float* __restrict__ psi, float* __restrict__ alpha)
{
    __shared__ float s_x[TM][C];
    __shared__ float s_h[TM][C];
    const int c  = threadIdx.x;
    const int r0 = blockIdx.x * TM;

    #pragma unroll
    for (int r = 0; r < TM; ++r)
        s_x[r][c] = x[(size_t)(r0 + r) * C + c];
    __syncthreads();

    float acc[TM];
    // ---- h = x @ Wt + bt -> s_h
    #pragma unroll
    for (int r = 0; r < TM; ++r) acc[r] = 0.f;
    for (int e4 = 0; e4 < C; e4 += 4) {
        const float w0 = Wt[(e4+0)*C + c], w1 = Wt[(e4+1)*C + c];
        const float w2 = Wt[(e4+2)*C + c], w3 = Wt[(e4+3)*C + c];
        #pragma unroll
        for (int r = 0; r < TM; ++r) {
            const float4 xv = *(const float4*)&s_x[r][e4];
            acc[r] = fmaf(xv.x, w0, acc[r]);
            acc[r] = fmaf(xv.y, w1, acc[r]);
            acc[r] = fmaf(xv.z, w2, acc[r]);
            acc[r] = fmaf(xv.w, w3, acc[r]);
        }
    }
    {
        const float bb = bt[c];
        #pragma unroll
        for (int r = 0; r < TM; ++r) s_h[r][c] = acc[r] + bb;
    }
    __syncthreads();

    // ---- phi / psi / alpha = h @ W + b  (three GEMMs, macro to keep
    //      pointers compile-time so nothing spills to scratch)
#define OUT_GEMM(W_, b_, o_)                                                  \
    {                                                                         \
        _Pragma("unroll")                                                     \
        for (int r = 0; r < TM; ++r) acc[r] = 0.f;                            \
        for (int e4 = 0; e4 < C; e4 += 4) {                                   \
            const float w0 = W_[(e4+0)*C + c], w1 = W_[(e4+1)*C + c];         \
            const float w2 = W_[(e4+2)*C + c], w3 = W_[(e4+3)*C + c];         \
            _Pragma("unroll")                                                 \
            for (int r = 0; r < TM; ++r) {                                    \
                const float4 hv = *(const float4*)&s_h[r][e4];                \
                acc[r] = fmaf(hv.x, w0, acc[r]);                              \
                acc[r] = fmaf(hv.y, w1, acc[r]);                              \
                acc[r] = fmaf(hv.z, w2, acc[r]);                              \
                acc[r] = fmaf(hv.w, w3, acc[r]);                              \
            }                                                                 \
        }                                                                     \
        const float bb = b_[c];                                               \
        _Pragma("unroll")                                                     \
        for (int r = 0; r < TM; ++r)                                          \
            o_[(size_t)(r0 + r) * C + c] = acc[r] + bb;                       \
    }
    OUT_GEMM(Wp, bp, phi)
    OUT_GEMM(Ws, bs, psi)
    OUT_GEMM(Wa, ba, alpha)
#undef OUT_GEMM
}

// ---------------------------------------------------------------------------
// Kernel 2: fused per-point vector attention + W_down + residual.
// One 128-thread block per point. Thread c owns channel c.
// LDS tiles (16 x 128): sA = t1/u, sB = pos, sCt = attn_in, sD = alpha_j.
// logits/softmax fully in registers (16 per thread).
// ---------------------------------------------------------------------------
__global__ __launch_bounds__(128) void k_attn(
    const float* __restrict__ phi, const float* __restrict__ psi,
    const float* __restrict__ alpha,
    const float* __restrict__ coords, const int* __restrict__ nidx,
    const float* __restrict__ Wd1, const float* __restrict__ bd1,
    const float* __restrict__ Wd2, const float* __restrict__ bd2,
    const float* __restrict__ Wg1, const float* __restrict__ bg1,
    const float* __restrict__ Wg2, const float* __restrict__ bg2,
    const float* __restrict__ Wdn, const float* __restrict__ bdn,
    const float* __restrict__ x, float* __restrict__ out)
{
    __shared__ float sA[K][C];     // t1, later u
    __shared__ float sB[K][C];     // pos
    __shared__ float sCt[K][C];    // attn_in
    __shared__ float sD[K][C];     // gathered alpha
    __shared__ float s_rel[K][4];
    __shared__ int   s_idx[K];
    __shared__ float s_y[C];

    const int c = threadIdx.x;
    const int n = blockIdx.x;

    if (c < K) {
        const int j = nidx[(size_t)n * K + c];
        s_idx[c] = j;
        s_rel[c][0] = coords[(size_t)n*3+0] - coords[(size_t)j*3+0];
        s_rel[c][1] = coords[(size_t)n*3+1] - coords[(size_t)j*3+1];
        s_rel[c][2] = coords[(size_t)n*3+2] - coords[(size_t)j*3+2];
    }
    const float phic = phi[(size_t)n*C + c];
    __syncthreads();

    // ---- gather psi/alpha, attn_in partial = phi - psi_j; t1 = relu(rel@Wd1+b)
    {
        const float w0 = Wd1[0*C+c], w1 = Wd1[1*C+c], w2 = Wd1[2*C+c];
        const float bb = bd1[c];
        #pragma unroll
        for (int k = 0; k < K; ++k) {
            const int j = s_idx[k];
            sCt[k][c] = phic - psi[(size_t)j*C + c];
            sD[k][c]  = alpha[(size_t)j*C + c];
            const float t = fmaf(s_rel[k][0], w0,
                            fmaf(s_rel[k][1], w1,
                            fmaf(s_rel[k][2], w2, bb)));
            sA[k][c] = fmaxf(t, 0.f);
        }
    }
    __syncthreads();

    // ---- pos = t1 @ Wd2 + bd2 -> sB ; attn_in += pos
    {
        float acc[K];
        #pragma unroll
        for (int k = 0; k < K; ++k) acc[k] = 0.f;
        for (int e4 = 0; e4 < C; e4 += 4) {
            const float v0 = Wd2[(e4+0)*C+c], v1 = Wd2[(e4+1)*C+c];
            const float v2 = Wd2[(e4+2)*C+c], v3 = Wd2[(e4+3)*C+c];
            #pragma unroll
            for (int k = 0; k < K; ++k) {
                const float4 a = *(const float4*)&sA[k][e4];
                acc[k] = fmaf(a.x, v0, acc[k]);
                acc[k] = fmaf(a.y, v1, acc[k]);
                acc[k] = fmaf(a.z, v2, acc[k]);
                acc[k] = fmaf(a.w, v3, acc[k]);
            }
        }
        const float bb = bd2[c];
        #pragma unroll
        for (int k = 0; k < K; ++k) {
            const float p = acc[k] + bb;
            sB[k][c]  = p;
            sCt[k][c] += p;
        }
    }
    __syncthreads();

    // ---- u = relu(attn_in @ Wg1 + bg1) -> sA (overwrites t1; t1 consumed)
    {
        float acc[K];
        #pragma unroll
        for (int k = 0; k < K; ++k) acc[k] = 0.f;
        for (int e4 = 0; e4 < C; e4 += 4) {
            const float v0 = Wg1[(e4+0)*C+c], v1 = Wg1[(e4+1)*C+c];
            const float v2 = Wg1[(e4+2)*C+c], v3 = Wg1[(e4+3)*C+c];
            #pragma unroll
            for (int k = 0; k < K; ++k) {
                const float4 a = *(const float4*)&sCt[k][e4];
                acc[k] = fmaf(a.x, v0, acc[k]);
                acc[k] = fmaf(a.y, v1, acc[k]);
                acc[k] = fmaf(a.z, v2, acc[k]);
                acc[k] = fmaf(a.w, v3, acc[k]);
            }
        }
        const float bb = bg1[c];
        #pragma unroll
        for (int k = 0; k < K; ++k) sA[k][c] = fmaxf(acc[k] + bb, 0.f);
    }
    __syncthreads();

    // ---- logits = u @ Wg2 + bg2 (registers); softmax over k; y
    {
        float lg[K];
        #pragma unroll
        for (int k = 0; k < K; ++k) lg[k] = 0.f;
        for (int e4 = 0; e4 < C; e4 += 4) {
            const float v0 = Wg2[(e4+0)*C+c], v1 = Wg2[(e4+1)*C+c];
            const float v2 = Wg2[(e4+2)*C+c], v3 = Wg2[(e4+3)*C+c];
            #pragma unroll
            for (int k = 0; k < K; ++k) {
                const float4 a = *(const float4*)&sA[k][e4];
                lg[k] = fmaf(a.x, v0, lg[k]);
                lg[k] = fmaf(a.y, v1, lg[k]);
                lg[k] = fmaf(a.z, v2, lg[k]);
                lg[k] = fmaf(a.w, v3, lg[k]);
            }
        }
        const float bb = bg2[c];
        float m = -1e30f;
        #pragma unroll
        for (int k = 0; k < K; ++k) { lg[k] += bb; m = fmaxf(m, lg[k]); }
        float den = 0.f;
        #pragma unroll
        for (int k = 0; k < K; ++k) { lg[k] = __expf(lg[k] - m); den += lg[k]; }
        const float inv = 1.0f / den;
        float y = 0.f;
        #pragma unroll
        for (int k = 0; k < K; ++k)
            y = fmaf(lg[k] * inv, sD[k][c] + sB[k][c], y);
        s_y[c] = y;
    }
    __syncthreads();

    // ---- out = y @ Wdn + bdn + x  (row-local, fused)
    {
        float o = 0.f;
        for (int e4 = 0; e4 < C; e4 += 4) {
            const float4 yv = *(const float4*)&s_y[e4];
            o = fmaf(yv.x, Wdn[(e4+0)*C+c], o);
            o = fmaf(yv.y, Wdn[(e4+1)*C+c], o);
            o = fmaf(yv.z, Wdn[(e4+2)*C+c], o);
            o = fmaf(yv.w, Wdn[(e4+3)*C+c], o);
        }
        out[(size_t)n*C + c] = o + bdn[c] + x[(size_t)n*C + c];
    }
}

// ---------------------------------------------------------------------------
extern "C" void kernel_launch(void* const* d_in, const int* in_sizes, int n_in,
                              void* d_out, int out_size, void* d_ws, size_t ws_size,
                              hipStream_t stream)
{
    const float* x      = (const float*)d_in[0];
    const float* coords = (const float*)d_in[1];
    const int*   nidx   = (const int*)d_in[2];
    const float* W_top  = (const float*)d_in[3];
    const float* b_top  = (const float*)d_in[4];
    const float* W_down = (const float*)d_in[5];
    const float* b_down = (const float*)d_in[6];
    const float* W_phi  = (const float*)d_in[7];
    const float* b_phi  = (const float*)d_in[8];
    const float* W_psi  = (const float*)d_in[9];
    const float* b_psi  = (const float*)d_in[10];
    const float* W_alpha= (const float*)d_in[11];
    const float* b_alpha= (const float*)d_in[12];
    const float* W_d1   = (const float*)d_in[13];
    const float* b_d1   = (const float*)d_in[14];
    const float* W_d2   = (const float*)d_in[15];
    const float* b_d2   = (const float*)d_in[16];
    const float* W_g1   = (const float*)d_in[17];
    const float* b_g1   = (const float*)d_in[18];
    const float* W_g2   = (const float*)d_in[19];
    const float* b_g2   = (const float*)d_in[20];

    const int N = in_sizes[0] / C;

    float* phi   = (float*)d_ws;
    float* psi   = phi + (size_t)N * C;
    float* alpha = psi + (size_t)N * C;
    float* out   = (float*)d_out;

    hipLaunchKernelGGL(k_qkv, dim3(N / TM), dim3(C), 0, stream,
        x, W_top, b_top, W_phi, b_phi, W_psi, b_psi, W_alpha, b_alpha,
        phi, psi, alpha);

    hipLaunchKernelGGL(k_attn, dim3(N), dim3(C), 0, stream,
        phi, psi, alpha, coords, nidx,
        W_d1, b_d1, W_d2, b_d2, W_g1, b_g1, W_g2, b_g2,
        W_down, b_down, x, out);
}

// Round 2
// 938.436 us; speedup vs baseline: 2.8109x; 2.8109x over previous
//
#include <hip/hip_runtime.h>
#include <math.h>

#define C 128
#define K 16
#define TM 32

typedef unsigned short ushort_t;
typedef unsigned int u32;
typedef float f32x4 __attribute__((ext_vector_type(4)));
typedef _Float16 f16x8 __attribute__((ext_vector_type(8)));

union U4 { _Float16 h[4]; uint2 u; };

__device__ __forceinline__ float f16tof(ushort_t b) {
    _Float16 h = __builtin_bit_cast(_Float16, b); return (float)h;
}
__device__ __forceinline__ ushort_t ftof16(float f) {
    _Float16 h = (_Float16)f; return __builtin_bit_cast(ushort_t, h);
}

// ---------------------------------------------------------------------------
// Kernel 1: h = x@W_top + b; phi/psi/alpha = h@W_* + b  -> fp16 outputs
// ---------------------------------------------------------------------------
__global__ __launch_bounds__(128) void k_qkv(
    const float* __restrict__ x,
    const float* __restrict__ Wt, const float* __restrict__ bt,
    const float* __restrict__ Wp, const float* __restrict__ bp,
    const float* __restrict__ Ws, const float* __restrict__ bs,
    const float* __restrict__ Wa, const float* __restrict__ ba,
    ushort_t* __restrict__ phi, ushort_t* __restrict__ psi, ushort_t* __restrict__ alpha)
{
    __shared__ float s_x[TM][C];
    __shared__ float s_h[TM][C];
    const int c  = threadIdx.x;
    const int r0 = blockIdx.x * TM;

    #pragma unroll
    for (int r = 0; r < TM; ++r)
        s_x[r][c] = x[(size_t)(r0 + r) * C + c];
    __syncthreads();

    float acc[TM];
    #pragma unroll
    for (int r = 0; r < TM; ++r) acc[r] = 0.f;
    for (int e4 = 0; e4 < C; e4 += 4) {
        const float w0 = Wt[(e4+0)*C + c], w1 = Wt[(e4+1)*C + c];
        const float w2 = Wt[(e4+2)*C + c], w3 = Wt[(e4+3)*C + c];
        #pragma unroll
        for (int r = 0; r < TM; ++r) {
            const float4 xv = *(const float4*)&s_x[r][e4];
            acc[r] = fmaf(xv.x, w0, acc[r]);
            acc[r] = fmaf(xv.y, w1, acc[r]);
            acc[r] = fmaf(xv.z, w2, acc[r]);
            acc[r] = fmaf(xv.w, w3, acc[r]);
        }
    }
    {
        const float bb = bt[c];
        #pragma unroll
        for (int r = 0; r < TM; ++r) s_h[r][c] = acc[r] + bb;
    }
    __syncthreads();

#define OUT_GEMM(W_, b_, o_)                                                  \
    {                                                                         \
        _Pragma("unroll")                                                     \
        for (int r = 0; r < TM; ++r) acc[r] = 0.f;                            \
        for (int e4 = 0; e4 < C; e4 += 4) {                                   \
            const float w0 = W_[(e4+0)*C + c], w1 = W_[(e4+1)*C + c];         \
            const float w2 = W_[(e4+2)*C + c], w3 = W_[(e4+3)*C + c];         \
            _Pragma("unroll")                                                 \
            for (int r = 0; r < TM; ++r) {                                    \
                const float4 hv = *(const float4*)&s_h[r][e4];                \
                acc[r] = fmaf(hv.x, w0, acc[r]);                              \
                acc[r] = fmaf(hv.y, w1, acc[r]);                              \
                acc[r] = fmaf(hv.z, w2, acc[r]);                              \
                acc[r] = fmaf(hv.w, w3, acc[r]);                              \
            }                                                                 \
        }                                                                     \
        const float bb = b_[c];                                               \
        _Pragma("unroll")                                                     \
        for (int r = 0; r < TM; ++r)                                          \
            o_[(size_t)(r0 + r) * C + c] = ftof16(acc[r] + bb);               \
    }
    OUT_GEMM(Wp, bp, phi)
    OUT_GEMM(Ws, bs, psi)
    OUT_GEMM(Wa, ba, alpha)
#undef OUT_GEMM
}

// ---------------------------------------------------------------------------
// Prep: transpose+convert W_d2, W_g1, W_g2, W_down to fp16  WT[n][e]
// ---------------------------------------------------------------------------
__global__ __launch_bounds__(128) void k_prep(
    const float* __restrict__ s0, const float* __restrict__ s1,
    const float* __restrict__ s2, const float* __restrict__ s3,
    ushort_t* __restrict__ d0, ushort_t* __restrict__ d1,
    ushort_t* __restrict__ d2, ushort_t* __restrict__ d3)
{
    const int m = blockIdx.x >> 7, n = blockIdx.x & 127, e = threadIdx.x;
    const float* s = (m==0) ? s0 : (m==1) ? s1 : (m==2) ? s2 : s3;
    ushort_t*   d = (m==0) ? d0 : (m==1) ? d1 : (m==2) ? d2 : d3;
    d[n*C + e] = ftof16(s[e*C + n]);
}

// ---------------------------------------------------------------------------
// Kernel 2: fused vector attention, MFMA fp16 hi/lo split.
// 512 threads = 8 waves; wave w owns output cols [16w,16w+16).
// A-tiles (16x128) in XOR-swizzled LDS; weight B-frags in registers.
// ---------------------------------------------------------------------------
__global__ __launch_bounds__(512, 2) void k_attn2(
    const ushort_t* __restrict__ phiB, const ushort_t* __restrict__ psiB,
    const ushort_t* __restrict__ alfB,
    const float* __restrict__ coords, const int* __restrict__ nidx,
    const float* __restrict__ Wd1, const float* __restrict__ bd1,
    const ushort_t* __restrict__ WTd2, const float* __restrict__ bd2,
    const ushort_t* __restrict__ WTg1, const float* __restrict__ bg1,
    const ushort_t* __restrict__ WTg2,
    const ushort_t* __restrict__ WTdn, const float* __restrict__ bdn,
    const float* __restrict__ x, float* __restrict__ out,
    int npts, int ppb)
{
    __shared__ ushort_t sThi[2048], sTlo[2048];
    __shared__ ushort_t sAhi[2048], sAlo[2048];
    __shared__ ushort_t sUhi[2048], sUlo[2048];
    __shared__ ushort_t sPsi[16][136], sAlf[16][136];
    __shared__ ushort_t sPhi[2][128];
    __shared__ float    sRel[2][16][3];
    __shared__ int      sIdx[2][16];
    __shared__ float    sY[128];

    const int tid   = threadIdx.x;
    const int lane  = tid & 63;
    const int wv    = tid >> 6;
    const int ncol  = (wv << 4) + (lane & 15);   // this wave+lane's output col
    const int arow  = lane & 15;                 // A-frag row
    const int kgrp  = lane >> 4;                 // 0..3
    const int krow0 = kgrp << 3;
    const int r_g   = tid >> 5;                  // gather row 0..15
    const int c4    = (tid & 31) << 2;           // gather col group (4 ch)

    // persistent weight fragments (fp16)
    f16x8 wd2[4], wg1[4], wg2[4], wdn[4];
    #pragma unroll
    for (int kk = 0; kk < 4; ++kk) {
        wd2[kk] = *(const f16x8*)&WTd2[(size_t)ncol*C + (kk<<5) + krow0];
        wg1[kk] = *(const f16x8*)&WTg1[(size_t)ncol*C + (kk<<5) + krow0];
        wg2[kk] = *(const f16x8*)&WTg2[(size_t)ncol*C + (kk<<5) + krow0];
    }
    #pragma unroll
    for (int z = 0; z < 4; ++z)
        wdn[z] = *(const f16x8*)&WTdn[(size_t)ncol*C + (kgrp<<5) + (z<<3)];
    const float bd2c = bd2[ncol], bg1c = bg1[ncol], bdnc = bdn[ncol];

    // Wd1/bd1 columns cached in registers (used every point)
    float w1r0[4], w1r1[4], w1r2[4], b1r[4];
    #pragma unroll
    for (int z = 0; z < 4; ++z) {
        w1r0[z] = Wd1[0*C + c4 + z];
        w1r1[z] = Wd1[1*C + c4 + z];
        w1r2[z] = Wd1[2*C + c4 + z];
        b1r[z]  = bd1[c4 + z];
    }

    const int p0   = blockIdx.x * ppb;
    if (p0 >= npts) return;
    const int pend = (p0 + ppb < npts) ? (p0 + ppb) : npts;

    // ---- prologue: idx/rel/phi for p0, issue p0 gathers
    if (tid < K) {
        const int j = nidx[(size_t)p0*K + tid];
        sIdx[0][tid] = j;
        sRel[0][tid][0] = coords[(size_t)p0*3+0] - coords[(size_t)j*3+0];
        sRel[0][tid][1] = coords[(size_t)p0*3+1] - coords[(size_t)j*3+1];
        sRel[0][tid][2] = coords[(size_t)p0*3+2] - coords[(size_t)j*3+2];
    } else if (tid >= 64 && tid < 128) {
        *(u32*)&sPhi[0][(tid-64)<<1] = *(const u32*)&phiB[(size_t)p0*C + ((tid-64)<<1)];
    }
    __syncthreads();
    uint2 stPsi, stAlf;
    {
        const int jj = sIdx[0][r_g];
        stPsi = *(const uint2*)&psiB[(size_t)jj*C + c4];
        stAlf = *(const uint2*)&alfB[(size_t)jj*C + c4];
    }

    int idxReg = 0; u32 phiReg = 0;
    float cn0=0, cn1=0, cn2=0, cj0=0, cj1=0, cj2=0;

    for (int p = p0; p < pend; ++p) {
        const int b = p & 1, b2 = b ^ 1;
        const int np1 = p + 1;
        const bool hn = (np1 < pend);

        // 1: commit staged gathers to LDS
        *(uint2*)&sPsi[r_g][c4] = stPsi;
        *(uint2*)&sAlf[r_g][c4] = stAlf;

        // 2: issue next-point idx / own-coords / phi prefetch
        if (hn) {
            if (tid < K) {
                idxReg = nidx[(size_t)np1*K + tid];
                cn0 = coords[(size_t)np1*3+0];
                cn1 = coords[(size_t)np1*3+1];
                cn2 = coords[(size_t)np1*3+2];
            } else if (tid < 128) {
                phiReg = *(const u32*)&phiB[(size_t)np1*C + ((tid-64)<<1)];
            }
        }

        // 3: t1 = relu(rel @ Wd1 + bd1) -> hi/lo tiles
        {
            const float r0v = sRel[b][r_g][0], r1v = sRel[b][r_g][1], r2v = sRel[b][r_g][2];
            U4 hi, lo;
            #pragma unroll
            for (int z = 0; z < 4; ++z) {
                float t = fmaf(r0v, w1r0[z], fmaf(r1v, w1r1[z], fmaf(r2v, w1r2[z], b1r[z])));
                t = fmaxf(t, 0.f);
                const _Float16 h = (_Float16)t;
                hi.h[z] = h;
                lo.h[z] = (_Float16)(t - (float)h);
            }
            const int sidx = (r_g<<7) + (c4 ^ ((r_g&7)<<3));
            *(uint2*)&sThi[sidx] = hi.u;
            *(uint2*)&sTlo[sidx] = lo.u;
        }
        __syncthreads();                                   // S1

        // 5: pos = t1 @ Wd2 + bd2
        f32x4 pos = {0.f, 0.f, 0.f, 0.f};
        #pragma unroll
        for (int kk = 0; kk < 4; ++kk) {
            const int sidx = (arow<<7) + (((kk<<5) + krow0) ^ ((arow&7)<<3));
            pos = __builtin_amdgcn_mfma_f32_16x16x32_f16(*(const f16x8*)&sThi[sidx], wd2[kk], pos, 0,0,0);
            pos = __builtin_amdgcn_mfma_f32_16x16x32_f16(*(const f16x8*)&sTlo[sidx], wd2[kk], pos, 0,0,0);
        }
        #pragma unroll
        for (int z = 0; z < 4; ++z) pos[z] += bd2c;

        // 6: attn_in = phi - psi + pos -> hi/lo tiles (C-layout -> swizzled LDS)
        {
            const float phic = f16tof(sPhi[b][ncol]);
            #pragma unroll
            for (int reg = 0; reg < 4; ++reg) {
                const int rrw = (kgrp<<2) + reg;
                const float av = phic - f16tof(sPsi[rrw][ncol]) + pos[reg];
                const _Float16 h = (_Float16)av;
                const int sidx = (rrw<<7) + (ncol ^ ((rrw&7)<<3));
                sAhi[sidx] = __builtin_bit_cast(ushort_t, h);
                sAlo[sidx] = ftof16(av - (float)h);
            }
        }

        // 7: stash next idx/phi; issue coords[j] loads
        if (hn) {
            if (tid < K) {
                const int j2 = idxReg;
                sIdx[b2][tid] = j2;
                cj0 = coords[(size_t)j2*3+0];
                cj1 = coords[(size_t)j2*3+1];
                cj2 = coords[(size_t)j2*3+2];
            } else if (tid < 128) {
                *(u32*)&sPhi[b2][(tid-64)<<1] = phiReg;
            }
        }
        __syncthreads();                                   // S2

        // 9: u = relu(attn @ Wg1 + bg1) -> hi/lo tiles
        {
            f32x4 ua = {0.f, 0.f, 0.f, 0.f};
            #pragma unroll
            for (int kk = 0; kk < 4; ++kk) {
                const int sidx = (arow<<7) + (((kk<<5) + krow0) ^ ((arow&7)<<3));
                ua = __builtin_amdgcn_mfma_f32_16x16x32_f16(*(const f16x8*)&sAhi[sidx], wg1[kk], ua, 0,0,0);
                ua = __builtin_amdgcn_mfma_f32_16x16x32_f16(*(const f16x8*)&sAlo[sidx], wg1[kk], ua, 0,0,0);
            }
            #pragma unroll
            for (int reg = 0; reg < 4; ++reg) {
                const float uv = fmaxf(ua[reg] + bg1c, 0.f);
                const _Float16 h = (_Float16)uv;
                const int rrw = (kgrp<<2) + reg;
                const int sidx = (rrw<<7) + (ncol ^ ((rrw&7)<<3));
                sUhi[sidx] = __builtin_bit_cast(ushort_t, h);
                sUlo[sidx] = ftof16(uv - (float)h);
            }
        }
        __syncthreads();                                   // S3

        // 11: logits = u @ Wg2   (b_g2 dropped: softmax shift-invariant)
        f32x4 lg = {0.f, 0.f, 0.f, 0.f};
        #pragma unroll
        for (int kk = 0; kk < 4; ++kk) {
            const int sidx = (arow<<7) + (((kk<<5) + krow0) ^ ((arow&7)<<3));
            lg = __builtin_amdgcn_mfma_f32_16x16x32_f16(*(const f16x8*)&sUhi[sidx], wg2[kk], lg, 0,0,0);
            lg = __builtin_amdgcn_mfma_f32_16x16x32_f16(*(const f16x8*)&sUlo[sidx], wg2[kk], lg, 0,0,0);
        }

        // 12: softmax over the 16 neighbors (per column)
        float m = fmaxf(fmaxf(lg[0], lg[1]), fmaxf(lg[2], lg[3]));
        m = fmaxf(m, __shfl_xor(m, 16));
        m = fmaxf(m, __shfl_xor(m, 32));
        const float e0v = __expf(lg[0]-m), e1v = __expf(lg[1]-m);
        const float e2v = __expf(lg[2]-m), e3v = __expf(lg[3]-m);
        float den = e0v + e1v + e2v + e3v;
        den += __shfl_xor(den, 16);
        den += __shfl_xor(den, 32);
        const float inv = 1.0f / den;

        // 13: y = sum_k w_k * (alpha_k + pos_k)
        {
            const int rr0 = kgrp << 2;
            float yp;
            yp  = e0v * (f16tof(sAlf[rr0+0][ncol]) + pos[0]);
            yp += e1v * (f16tof(sAlf[rr0+1][ncol]) + pos[1]);
            yp += e2v * (f16tof(sAlf[rr0+2][ncol]) + pos[2]);
            yp += e3v * (f16tof(sAlf[rr0+3][ncol]) + pos[3]);
            yp *= inv;
            yp += __shfl_xor(yp, 16);
            yp += __shfl_xor(yp, 32);
            if (lane < 16) sY[ncol] = yp;
        }

        // 14: issue gathers + rel for next point
        if (hn) {
            const int jj = sIdx[b2][r_g];
            stPsi = *(const uint2*)&psiB[(size_t)jj*C + c4];
            stAlf = *(const uint2*)&alfB[(size_t)jj*C + c4];
            if (tid < K) {
                sRel[b2][tid][0] = cn0 - cj0;
                sRel[b2][tid][1] = cn1 - cj1;
                sRel[b2][tid][2] = cn2 - cj2;
            }
        }
        __syncthreads();                                   // S4

        // 16: out = y @ W_down + b_down + x
        {
            float acc = 0.f;
            const int e0i = kgrp << 5;
            #pragma unroll
            for (int z = 0; z < 4; ++z) {
                const float4 ya = *(const float4*)&sY[e0i + (z<<3)];
                const float4 yb = *(const float4*)&sY[e0i + (z<<3) + 4];
                const f16x8 w8 = wdn[z];
                acc = fmaf(ya.x, (float)w8[0], acc);
                acc = fmaf(ya.y, (float)w8[1], acc);
                acc = fmaf(ya.z, (float)w8[2], acc);
                acc = fmaf(ya.w, (float)w8[3], acc);
                acc = fmaf(yb.x, (float)w8[4], acc);
                acc = fmaf(yb.y, (float)w8[5], acc);
                acc = fmaf(yb.z, (float)w8[6], acc);
                acc = fmaf(yb.w, (float)w8[7], acc);
            }
            acc += __shfl_xor(acc, 16);
            acc += __shfl_xor(acc, 32);
            if (lane < 16)
                out[(size_t)p*C + ncol] = acc + bdnc + x[(size_t)p*C + ncol];
        }
    }
}

// ---------------------------------------------------------------------------
extern "C" void kernel_launch(void* const* d_in, const int* in_sizes, int n_in,
                              void* d_out, int out_size, void* d_ws, size_t ws_size,
                              hipStream_t stream)
{
    const float* x      = (const float*)d_in[0];
    const float* coords = (const float*)d_in[1];
    const int*   nidx   = (const int*)d_in[2];
    const float* W_top  = (const float*)d_in[3];
    const float* b_top  = (const float*)d_in[4];
    const float* W_down = (const float*)d_in[5];
    const float* b_down = (const float*)d_in[6];
    const float* W_phi  = (const float*)d_in[7];
    const float* b_phi  = (const float*)d_in[8];
    const float* W_psi  = (const float*)d_in[9];
    const float* b_psi  = (const float*)d_in[10];
    const float* W_alpha= (const float*)d_in[11];
    const float* b_alpha= (const float*)d_in[12];
    const float* W_d1   = (const float*)d_in[13];
    const float* b_d1   = (const float*)d_in[14];
    const float* W_d2   = (const float*)d_in[15];
    const float* b_d2   = (const float*)d_in[16];
    const float* W_g1   = (const float*)d_in[17];
    const float* b_g1   = (const float*)d_in[18];
    const float* W_g2   = (const float*)d_in[19];
    const float* b_g2   = (const float*)d_in[20];
    (void)b_g2; // softmax shift-invariant

    const int N = in_sizes[0] / C;

    ushort_t* WTd2 = (ushort_t*)d_ws;
    ushort_t* WTg1 = WTd2 + C*C;
    ushort_t* WTg2 = WTg1 + C*C;
    ushort_t* WTdn = WTg2 + C*C;
    ushort_t* phiB = WTdn + C*C;
    ushort_t* psiB = phiB + (size_t)N*C;
    ushort_t* alfB = psiB + (size_t)N*C;
    float* out = (float*)d_out;

    hipLaunchKernelGGL(k_prep, dim3(4*C), dim3(C), 0, stream,
        W_d2, W_g1, W_g2, W_down, WTd2, WTg1, WTg2, WTdn);

    hipLaunchKernelGGL(k_qkv, dim3(N / TM), dim3(C), 0, stream,
        x, W_top, b_top, W_phi, b_phi, W_psi, b_psi, W_alpha, b_alpha,
        phiB, psiB, alfB);

    const int NBLK = 4096;
    const int ppb = (N + NBLK - 1) / NBLK;
    hipLaunchKernelGGL(k_attn2, dim3(NBLK), dim3(512), 0, stream,
        phiB, psiB, alfB, coords, nidx,
        W_d1, b_d1, WTd2, b_d2, WTg1, b_g1, WTg2,
        WTdn, b_down, x, out, N, ppb);
}